// Round 11
// baseline (211.355 us; speedup 1.0000x reference)
//
#include <hip/hip_runtime.h>
#include <hip/hip_bf16.h>

#define NS 512
#define NB 2048
#define NT 32
#define NF 64
#define NH 128
#define NFX 80   // padded B cols: 64 bgX + y(64) + ones(65) + zeros(66..79)

// output float offsets: [leaf_xs (S,T,F)][leaf_y (S,T)][alphas (S,B,T)]
#define OY  ((size_t)NS * NT * NF)
#define OA  (OY + (size_t)NS * NT)

// prep grid partition
#define PACK_B 2048
#define ENC_B  1280
#define TR_B   32

typedef __attribute__((ext_vector_type(8))) short bf16x8;
typedef __attribute__((ext_vector_type(4))) float f32x4;

__device__ __forceinline__ unsigned short f2bfu(float x) {
    __hip_bfloat16 h = __float2bfloat16(x);
    return __builtin_bit_cast(unsigned short, h);
}

// bit j of result = (byte j of v != 0), j in [0,16)
__device__ __forceinline__ unsigned int pack16_bytes(uint4 v) {
    unsigned int r = 0;
    unsigned int xs[4] = {v.x, v.y, v.z, v.w};
    #pragma unroll
    for (int i = 0; i < 4; ++i) {
        unsigned int x = xs[i];
        unsigned int t = (x | ((x & 0x7F7F7F7Fu) + 0x7F7F7F7Fu)) & 0x80808080u;
        t >>= 7;
        unsigned int n = (t | (t >> 7) | (t >> 14) | (t >> 21)) & 0xFu;
        r |= n << (i * 4);
    }
    return r;
}

// ---------- prep: pack (0..2047, self-detecting) + encode (2 rows/block) + transpose ----------
__global__ __launch_bounds__(256) void prep_k(const void* mask,
        unsigned long long* pm,
        const float* __restrict__ X, const float* __restrict__ bgX,
        const float* __restrict__ bgy,
        const float* __restrict__ W1, const float* __restrict__ b1,
        const float* __restrict__ W2, const float* __restrict__ b2,
        float* __restrict__ enc, unsigned short* __restrict__ bgXT2) {
    __shared__ float cbuf[64 * 65];
    const int blk = blockIdx.x;
    const int tid = threadIdx.x;

    if (blk < PACK_B) {                  // ---- pack branch: 1 thread = 1 u64 word ----
        int* flagp = (int*)cbuf;
        if (tid == 0) *flagp = 0;
        __syncthreads();
        {
            uint4 v = ((const uint4*)mask)[tid];          // 256*16B = 4096B header
            if (((v.x | v.y | v.z | v.w) & 0xFFFFFF00u) != 0u) *flagp = 1;
        }
        __syncthreads();
        const int isbyte = *flagp;

        const int w = blk * 256 + tid;
        if (isbyte) {                    // 1-byte bool layout
            const uint4* mb = (const uint4*)mask;
            uint4 q0 = mb[(size_t)w * 4 + 0];
            uint4 q1 = mb[(size_t)w * 4 + 1];
            uint4 q2 = mb[(size_t)w * 4 + 2];
            uint4 q3 = mb[(size_t)w * 4 + 3];
            unsigned long long r =  (unsigned long long)pack16_bytes(q0)
                                 | ((unsigned long long)pack16_bytes(q1) << 16)
                                 | ((unsigned long long)pack16_bytes(q2) << 32)
                                 | ((unsigned long long)pack16_bytes(q3) << 48);
            pm[w] = r;
        } else {                         // int32 layout
            const uint4* mi = (const uint4*)mask;
            unsigned long long r = 0;
            #pragma unroll
            for (int i = 0; i < 16; ++i) {
                uint4 v = mi[(size_t)w * 16 + i];
                unsigned int b = (v.x ? 1u : 0u) | (v.y ? 2u : 0u) |
                                 (v.z ? 4u : 0u) | (v.w ? 8u : 0u);
                r |= (unsigned long long)b << (i * 4);
            }
            pm[w] = r;
        }
        return;
    }

    if (blk < PACK_B + ENC_B) {          // ---- encode branch: 2 rows per block ----
        const int r0 = (blk - PACK_B) * 2;
        float* xr = cbuf;                // [2][64]
        float* hr = cbuf + 128;          // [2][128]
        if (tid < 128) {
            int r = tid >> 6, c = tid & 63;
            int row = r0 + r;
            const float* src = (row < NS) ? (X + (size_t)row * NF)
                                          : (bgX + (size_t)(row - NS) * NF);
            xr[r * 64 + c] = src[c];
        }
        __syncthreads();
        const int j = tid & 127, h = tid >> 7;
        const float* xh = xr + h * 64;
        float a1 = b1[j];
        #pragma unroll 4
        for (int f = 0; f < NF; ++f)
            a1 = fmaf(xh[f], W1[f * NH + j], a1);
        hr[h * 128 + j] = tanhf(a1);
        __syncthreads();
        const float* hh = hr + h * 128;
        float a2 = b2[j];
        #pragma unroll 4
        for (int k = 0; k < NH; ++k)
            a2 = fmaf(hh[k], W2[k * NH + j], a2);
        enc[(size_t)(r0 + h) * NH + j] = a2;
        return;
    }

    {                                    // ---- transpose branch: 64 b's per block ----
        const int b0 = (blk - PACK_B - ENC_B) * 64;
        float (*t_lds)[65] = (float(*)[65])cbuf;
        #pragma unroll
        for (int it = 0; it < 4; ++it) {
            int idx = (it * 256 + tid) * 4;
            int r = idx >> 6, c = idx & 63;
            *(float4*)(&t_lds[r][c]) = *(const float4*)(bgX + (size_t)(b0 + r) * NF + c);
        }
        __syncthreads();
        const int f = tid >> 2, sg = (tid & 3) * 16;
        union { unsigned short u[16]; uint4 q[2]; } pk;
        #pragma unroll
        for (int i = 0; i < 16; ++i) pk.u[i] = f2bfu(t_lds[sg + i][f]);
        uint4* dst = (uint4*)(bgXT2 + (size_t)f * NB + b0 + sg);
        dst[0] = pk.q[0];
        dst[1] = pk.q[1];
        if (tid < 64) {                  // extra cols: y, ones, zeros
            int b = b0 + tid;
            bgXT2[(size_t)64 * NB + b] = f2bfu(bgy[b]);
            bgXT2[(size_t)65 * NB + b] = 0x3F80;          // bf16 1.0
            #pragma unroll
            for (int ff = 66; ff < NFX; ++ff) bgXT2[(size_t)ff * NB + b] = 0;
        }
    }
}

// ---------- dots = X_enc @ bg_enc^T, 64x64 tiles, K=128 in two 64-slices ----------
__global__ __launch_bounds__(256) void dots_k(const float* __restrict__ Xe,
        const float* __restrict__ Be, float* __restrict__ dots) {
    __shared__ float At[64 * 68];
    __shared__ float Bt[64 * 68];
    const int s0 = blockIdx.y * 64, b0 = blockIdx.x * 64;
    const int tid = threadIdx.x;
    const int ts = tid & 15, tb = tid >> 4;
    float acc[4][4] = {};
    for (int kt = 0; kt < 2; ++kt) {
        __syncthreads();
        #pragma unroll
        for (int it = 0; it < 4; ++it) {
            int idx = tid * 4 + it * 1024;
            int r = idx >> 6, k = idx & 63;
            *(float4*)(&At[r * 68 + k]) = *(const float4*)(Xe + (size_t)(s0 + r) * NH + kt * 64 + k);
            *(float4*)(&Bt[r * 68 + k]) = *(const float4*)(Be + (size_t)(b0 + r) * NH + kt * 64 + k);
        }
        __syncthreads();
        #pragma unroll 4
        for (int k = 0; k < 64; ++k) {
            float a[4], bv[4];
            #pragma unroll
            for (int i = 0; i < 4; ++i) a[i] = At[(ts + 16 * i) * 68 + k];
            #pragma unroll
            for (int jj = 0; jj < 4; ++jj) bv[jj] = Bt[(tb * 4 + jj) * 68 + k];
            #pragma unroll
            for (int i = 0; i < 4; ++i)
                #pragma unroll
                for (int jj = 0; jj < 4; ++jj)
                    acc[i][jj] = fmaf(a[i], bv[jj], acc[i][jj]);
        }
    }
    #pragma unroll
    for (int i = 0; i < 4; ++i) {
        float4 v = make_float4(acc[i][0], acc[i][1], acc[i][2], acc[i][3]);
        *(float4*)(&dots[(size_t)(s0 + ts + 16 * i) * NB + b0 + tb * 4]) = v;
    }
}

// ---------- softmax + MFMA einsum (xs|y|den fused via extended B), one block per s ----------
__global__ __launch_bounds__(256) void fusedA_k(float* __restrict__ dots,
        const unsigned long long* __restrict__ pmask,
        const unsigned short* __restrict__ bgXT2,
        float* __restrict__ rden_g, float* __restrict__ out) {
    __shared__ __align__(16) unsigned int mrow[NB];      // 8KB: mask bits, word b bit t
    __shared__ __align__(16) unsigned short e_bf[NB];    // 4KB: bf16(e)
    __shared__ float part[3 * NT * NFX];                 // 30KB: cross-wave partials
    __shared__ float wmax[4];
    __shared__ float rden_l[NT];
    __shared__ float ytmp[NT];

    const int s = blockIdx.x;
    const int tid = threadIdx.x;
    const int lane = tid & 63, w = tid >> 6;
    const int lo = lane & 15, hi = lane >> 4;

    // ---- phase 1: row max (shfl) + exp; e -> global f32 (for alphas_k) + LDS bf16 ----
    float* drow = dots + (size_t)s * NB;
    float4 d0 = *(const float4*)(drow + tid * 8);
    float4 d1 = *(const float4*)(drow + tid * 8 + 4);
    const uint4* pmrow = (const uint4*)((const unsigned int*)pmask + (size_t)s * NB);
    *(uint4*)(&mrow[tid * 4]) = pmrow[tid];
    *(uint4*)(&mrow[(tid + 256) * 4]) = pmrow[tid + 256];
    float pmax = fmaxf(fmaxf(fmaxf(d0.x, d0.y), fmaxf(d0.z, d0.w)),
                       fmaxf(fmaxf(d1.x, d1.y), fmaxf(d1.z, d1.w)));
    #pragma unroll
    for (int off = 32; off >= 1; off >>= 1)
        pmax = fmaxf(pmax, __shfl_xor(pmax, off, 64));
    if (lane == 0) wmax[w] = pmax;
    __syncthreads();
    const float Ms = fmaxf(fmaxf(wmax[0], wmax[1]), fmaxf(wmax[2], wmax[3]));
    float ev[8] = {d0.x, d0.y, d0.z, d0.w, d1.x, d1.y, d1.z, d1.w};
    union { unsigned short u[8]; uint4 q; } epk;
    #pragma unroll
    for (int q = 0; q < 8; ++q) { ev[q] = __expf(ev[q] - Ms); epk.u[q] = f2bfu(ev[q]); }
    *(float4*)(drow + tid * 8)     = make_float4(ev[0], ev[1], ev[2], ev[3]);
    *(float4*)(drow + tid * 8 + 4) = make_float4(ev[4], ev[5], ev[6], ev[7]);
    *(uint4*)(&e_bf[tid * 8]) = epk.q;
    __syncthreads();

    // ---- phase 2: MFMA over K (wave w owns b in [w*512, w*512+512)) ----
    f32x4 acc[2][5] = {};
    const unsigned short* bptr = bgXT2 + (size_t)lo * NB + w * 512 + hi * 8;
    #pragma unroll 2
    for (int ks = 0; ks < 16; ++ks) {
        const int bb = w * 512 + ks * 32 + hi * 8;
        uint4 ew4 = *(const uint4*)(&e_bf[bb]);
        uint4 m0 = *(const uint4*)(&mrow[bb]);
        uint4 m1 = *(const uint4*)(&mrow[bb + 4]);
        unsigned int ew[4] = {ew4.x, ew4.y, ew4.z, ew4.w};
        unsigned int mv[8] = {m0.x, m0.y, m0.z, m0.w, m1.x, m1.y, m1.z, m1.w};
        unsigned int A0[4], A1[4];
        #pragma unroll
        for (int p = 0; p < 4; ++p) {
            unsigned int mlo = mv[2 * p]     >> lo;
            unsigned int mhi = mv[2 * p + 1] >> lo;
            unsigned int k0 = ((mlo & 1u)       ? 0x0000FFFFu : 0u) |
                              ((mhi & 1u)       ? 0xFFFF0000u : 0u);
            unsigned int k1 = ((mlo & 0x10000u) ? 0x0000FFFFu : 0u) |
                              ((mhi & 0x10000u) ? 0xFFFF0000u : 0u);
            A0[p] = ew[p] & k0;
            A1[p] = ew[p] & k1;
        }
        bf16x8 a0 = __builtin_bit_cast(bf16x8, make_uint4(A0[0], A0[1], A0[2], A0[3]));
        bf16x8 a1 = __builtin_bit_cast(bf16x8, make_uint4(A1[0], A1[1], A1[2], A1[3]));
        #pragma unroll
        for (int n = 0; n < 5; ++n) {
            uint4 bv = *(const uint4*)(bptr + (size_t)n * 16 * NB + ks * 32);
            bf16x8 bfr = __builtin_bit_cast(bf16x8, bv);
            acc[0][n] = __builtin_amdgcn_mfma_f32_16x16x32_bf16(a0, bfr, acc[0][n], 0, 0, 0);
            acc[1][n] = __builtin_amdgcn_mfma_f32_16x16x32_bf16(a1, bfr, acc[1][n], 0, 0, 0);
        }
    }

    // ---- phase 3: cross-wave reduce; den/y from cols 65/64; write leaf_xs/leaf_y ----
    if (w > 0) {
        #pragma unroll
        for (int m = 0; m < 2; ++m)
            #pragma unroll
            for (int n = 0; n < 5; ++n)
                #pragma unroll
                for (int r = 0; r < 4; ++r) {
                    int t = m * 16 + hi * 4 + r, f = n * 16 + lo;
                    part[(w - 1) * (NT * NFX) + t * NFX + f] = acc[m][n][r];
                }
    }
    __syncthreads();
    if (w == 0) {
        #pragma unroll
        for (int m = 0; m < 2; ++m)
            #pragma unroll
            for (int r = 0; r < 4; ++r) {
                int t = m * 16 + hi * 4 + r;
                int o = t * NFX + 64 + lo;
                float tot = acc[m][4][r] + part[o] + part[NT * NFX + o] + part[2 * NT * NFX + o];
                if (lo == 0) ytmp[t] = tot;
                if (lo == 1) rden_l[t] = (tot > 0.f) ? 1.f / tot : 0.f;
            }
    }
    __syncthreads();
    if (w == 0) {
        float* xout = out + (size_t)s * NT * NF;
        #pragma unroll
        for (int m = 0; m < 2; ++m)
            #pragma unroll
            for (int n = 0; n < 4; ++n)
                #pragma unroll
                for (int r = 0; r < 4; ++r) {
                    int t = m * 16 + hi * 4 + r, f = n * 16 + lo;
                    int o = t * NFX + f;
                    float tot = acc[m][n][r] + part[o] + part[NT * NFX + o] + part[2 * NT * NFX + o];
                    xout[t * NF + f] = tot * rden_l[t];
                }
    }
    if (tid < 32) {
        out[OY + (size_t)s * NT + tid] = ytmp[tid] * rden_l[tid];
        rden_g[(size_t)s * NT + tid] = rden_l[tid];
    }
}

// ---------- alphas streaming write (MEASUREMENT: reps>1 repeats identical work; ----------
// asm liveness prevents cross-rep DSE; output identical every rep -> graph-safe)
__global__ __launch_bounds__(256) void alphas_k(const float* __restrict__ e,
        const unsigned int* __restrict__ pmask32, const float* __restrict__ rden_g,
        float* __restrict__ out, int reps) {
    const int tid = threadIdx.x;
    const int blk = blockIdx.x;               // 4096 blocks: (s, eighth)
    const int s = blk >> 3;
    const int tq = tid & 7;
    const f32x4 rd4 = *(const f32x4*)(rden_g + (size_t)s * NT + tq * 4);
    const float* erow = e + (size_t)s * NB;
    const unsigned int* mr = pmask32 + (size_t)s * NB;
    float* aout = out + OA + (size_t)s * NB * NT;
    const int b0 = (blk & 7) * 256 + (tid >> 3);

    for (int rep = 0; rep < reps; ++rep) {
        float ev[8];
        unsigned int mv[8];
        #pragma unroll
        for (int j = 0; j < 8; ++j) {
            ev[j] = erow[b0 + j * 32];
            mv[j] = mr[b0 + j * 32] >> (tq * 4);
            asm volatile("" : "+v"(ev[j]));    // keep live; block cross-rep folding/DSE
            asm volatile("" : "+v"(mv[j]));
        }
        #pragma unroll
        for (int j = 0; j < 8; ++j) {
            const int b = b0 + j * 32;
            f32x4 v;
            v.x = (mv[j] & 1u) ? ev[j] * rd4.x : 0.f;
            v.y = (mv[j] & 2u) ? ev[j] * rd4.y : 0.f;
            v.z = (mv[j] & 4u) ? ev[j] * rd4.z : 0.f;
            v.w = (mv[j] & 8u) ? ev[j] * rd4.w : 0.f;
            *(f32x4*)(aout + (size_t)b * NT + tq * 4) = v;
        }
    }
}

extern "C" void kernel_launch(void* const* d_in, const int* in_sizes, int n_in,
                              void* d_out, int out_size, void* d_ws, size_t ws_size,
                              hipStream_t stream) {
    (void)in_sizes; (void)n_in; (void)out_size; (void)ws_size;
    const float* X   = (const float*)d_in[0];
    const float* bgX = (const float*)d_in[1];
    const float* bgy = (const float*)d_in[2];
    const void*  nh  = d_in[3];
    const float* W1  = (const float*)d_in[4];
    const float* b1v = (const float*)d_in[5];
    const float* W2  = (const float*)d_in[6];
    const float* b2v = (const float*)d_in[7];
    float* out = (float*)d_out;
    char* ws = (char*)d_ws;

    // ws layout (bytes): [pad 4096][enc: 2560*128 f32 — rden_g overlays its head,
    //  safe: enc is dead after dots_k][dots/e: 512*2048 f32][pmask: 4MB u64][bgXT2: 80*2048 u16]
    float* enc = (float*)(ws + 4096);
    float* rden_g = (float*)(ws + 4096);   // overlays enc (enc consumed before fusedA writes)
    float* Xe = enc;
    float* Be = enc + (size_t)NS * NH;
    float* dots = (float*)(ws + 4096 + (size_t)(NS + NB) * NH * 4);
    unsigned long long* pmask = (unsigned long long*)((char*)dots + (size_t)NS * NB * 4);
    unsigned short* bgXT2 = (unsigned short*)((char*)pmask + (size_t)NS * NB * NT / 64 * 8);

    // MEASUREMENT ROUND: prep launched 2x (idempotent), alphas reps=4 (surfaces in top-5).
    // T = 2*Xp + Xd + Xf + 4*Xa + g; baseline 105.4 = Xp + Xd + Xf + Xa + g;
    // Xa = alphas_dur/4 from its counter row; => Xp = T - 105.4 - 3*Xa.
    prep_k<<<PACK_B + ENC_B + TR_B, 256, 0, stream>>>(nh, pmask, X, bgX, bgy,
                                                      W1, b1v, W2, b2v, enc, bgXT2);
    prep_k<<<PACK_B + ENC_B + TR_B, 256, 0, stream>>>(nh, pmask, X, bgX, bgy,
                                                      W1, b1v, W2, b2v, enc, bgXT2);
    dots_k<<<dim3(NB / 64, NS / 64), 256, 0, stream>>>(Xe, Be, dots);
    fusedA_k<<<NS, 256, 0, stream>>>(dots, pmask, bgXT2, rden_g, out);
    alphas_k<<<NS * 8, 256, 0, stream>>>(dots, (const unsigned int*)pmask, rden_g, out, 4);
}

// Round 12
// 98.319 us; speedup vs baseline: 2.1497x; 2.1497x over previous
//
#include <hip/hip_runtime.h>
#include <hip/hip_bf16.h>

#define NS 512
#define NB 2048
#define NT 32
#define NF 64
#define NH 128
#define NFX 80   // padded B cols: 64 bgX + y(64) + ones(65) + zeros(66..79)

// output float offsets: [leaf_xs (S,T,F)][leaf_y (S,T)][alphas (S,B,T)]
#define OY  ((size_t)NS * NT * NF)
#define OA  (OY + (size_t)NS * NT)

// prep grid partition
#define PACK_B 2048
#define ENC_B  1280
#define TR_B   32

typedef __attribute__((ext_vector_type(8))) short bf16x8;
typedef __attribute__((ext_vector_type(4))) float f32x4;

__device__ __forceinline__ unsigned short f2bfu(float x) {
    __hip_bfloat16 h = __float2bfloat16(x);
    return __builtin_bit_cast(unsigned short, h);
}

// bit j of result = (byte j of v != 0), j in [0,16)
__device__ __forceinline__ unsigned int pack16_bytes(uint4 v) {
    unsigned int r = 0;
    unsigned int xs[4] = {v.x, v.y, v.z, v.w};
    #pragma unroll
    for (int i = 0; i < 4; ++i) {
        unsigned int x = xs[i];
        unsigned int t = (x | ((x & 0x7F7F7F7Fu) + 0x7F7F7F7Fu)) & 0x80808080u;
        t >>= 7;
        unsigned int n = (t | (t >> 7) | (t >> 14) | (t >> 21)) & 0xFu;
        r |= n << (i * 4);
    }
    return r;
}

// ---------- prep: pack (wave-contiguous loads + shfl combine) + encode + frag-transpose ----------
__global__ __launch_bounds__(256) void prep_k(const void* mask,
        unsigned long long* pm,
        const float* __restrict__ X, const float* __restrict__ bgX,
        const float* __restrict__ bgy,
        const float* __restrict__ W1, const float* __restrict__ b1,
        const float* __restrict__ W2, const float* __restrict__ b2,
        float* __restrict__ enc, unsigned short* __restrict__ bgXT2) {
    __shared__ float cbuf[64 * 68];
    const int blk = blockIdx.x;
    const int tid = threadIdx.x;

    if (blk < PACK_B) {                  // ---- pack branch ----
        // per-block layout detect over fixed 4KB header (uniform result):
        int* flagp = (int*)cbuf;
        if (tid == 0) *flagp = 0;
        __syncthreads();
        {
            uint4 v = ((const uint4*)mask)[tid];          // 256*16B = 4096B header
            if (((v.x | v.y | v.z | v.w) & 0xFFFFFF00u) != 0u) *flagp = 1;
        }
        __syncthreads();
        const int isbyte = *flagp;

        const int wv = tid >> 6, lane = tid & 63;
        unsigned long long* pmw = pm + (size_t)blk * 256 + wv * 64;
        if (isbyte) {                    // 1-byte bool: wave covers 4KB contiguous
            const char* base = (const char*)mask + (size_t)blk * 16384 + wv * 4096;
            #pragma unroll
            for (int k = 0; k < 4; ++k) {
                uint4 q = *(const uint4*)(base + k * 1024 + lane * 16);  // 1KB/instr/wave
                unsigned int p = pack16_bytes(q);                        // 16 bits for my 16B
                unsigned int p1 = (unsigned int)__shfl_down((int)p, 1, 64);
                unsigned int r32 = p | (p1 << 16);
                unsigned int h32 = (unsigned int)__shfl_down((int)r32, 2, 64);
                if ((lane & 3) == 0)
                    pmw[k * 16 + (lane >> 2)] =
                        (unsigned long long)r32 | ((unsigned long long)h32 << 32);
            }
        } else {                         // int32: wave covers 16KB contiguous
            const char* base = (const char*)mask + (size_t)blk * 65536 + wv * 16384;
            #pragma unroll 4
            for (int k = 0; k < 16; ++k) {
                uint4 v = *(const uint4*)(base + k * 1024 + lane * 16);
                unsigned int r = (v.x ? 1u : 0u) | (v.y ? 2u : 0u) |
                                 (v.z ? 4u : 0u) | (v.w ? 8u : 0u);
                r |= ((unsigned int)__shfl_down((int)r, 1, 64)) << 4;
                r |= ((unsigned int)__shfl_down((int)r, 2, 64)) << 8;
                r |= ((unsigned int)__shfl_down((int)r, 4, 64)) << 16;
                unsigned long long r64 = (unsigned long long)r |
                    ((unsigned long long)(unsigned int)__shfl_down((int)r, 8, 64) << 32);
                if ((lane & 15) == 0)
                    pmw[k * 4 + (lane >> 4)] = r64;
            }
        }
        return;
    }

    if (blk < PACK_B + ENC_B) {          // ---- encode branch: 2 rows per block ----
        const int r0 = (blk - PACK_B) * 2;
        float* xr = cbuf;                // [2][64]
        float* hr = cbuf + 128;          // [2][128]
        if (tid < 128) {
            int r = tid >> 6, c = tid & 63;
            int row = r0 + r;
            const float* src = (row < NS) ? (X + (size_t)row * NF)
                                          : (bgX + (size_t)(row - NS) * NF);
            xr[r * 64 + c] = src[c];
        }
        __syncthreads();
        const int j = tid & 127, h = tid >> 7;
        const float* xh = xr + h * 64;
        float a1 = b1[j];
        #pragma unroll 4
        for (int f = 0; f < NF; ++f)
            a1 = fmaf(xh[f], W1[f * NH + j], a1);
        hr[h * 128 + j] = tanhf(a1);
        __syncthreads();
        const float* hh = hr + h * 128;
        float a2 = b2[j];
        #pragma unroll 4
        for (int k = 0; k < NH; ++k)
            a2 = fmaf(hh[k], W2[k * NH + j], a2);
        enc[(size_t)(r0 + h) * NH + j] = a2;
        return;
    }

    {   // ---- frag-transpose branch: 64 b's per block -> MFMA-fragment-ordered B ----
        const int bb0 = blk - PACK_B - ENC_B;     // 0..31
        const int b0 = bb0 * 64;
        float (*t_lds)[65] = (float(*)[65])cbuf;
        #pragma unroll
        for (int it = 0; it < 4; ++it) {
            int idx = (it * 256 + tid) * 4;
            int r = idx >> 6, c = idx & 63;
            *(float4*)(&t_lds[r][c]) = *(const float4*)(bgX + (size_t)(b0 + r) * NF + c);
        }
        __syncthreads();
        // fb[cg][n][lane] (uint4): lane l=(lo,hi), elem j = B[n*16+lo][cg*32+hi*8+j]
        uint4* fb = (uint4*)bgXT2;
        const int c2 = tid >> 7;                  // which 32-b chunk of this block
        const int cg = bb0 * 2 + c2;              // global chunk id, 0..63
        for (int idx = tid & 127; idx < 320; idx += 128) {
            const int n = idx >> 6, l = idx & 63;
            const int lo = l & 15, hi = l >> 4;
            union { unsigned short u[8]; uint4 q; } pk;
            if (n < 4) {
                #pragma unroll
                for (int j = 0; j < 8; ++j)
                    pk.u[j] = f2bfu(t_lds[c2 * 32 + hi * 8 + j][n * 16 + lo]);
            } else {
                #pragma unroll
                for (int j = 0; j < 8; ++j) {
                    if (lo == 0)      pk.u[j] = f2bfu(bgy[b0 + c2 * 32 + hi * 8 + j]);
                    else if (lo == 1) pk.u[j] = 0x3F80;       // bf16 1.0
                    else              pk.u[j] = 0;
                }
            }
            fb[((size_t)cg * 5 + n) * 64 + l] = pk.q;          // wave-contiguous store
        }
    }
}

// ---------- dots = X_enc @ bg_enc^T; contiguous stores (tb fast), k-major Bt ----------
__global__ __launch_bounds__(256) void dots_k(const float* __restrict__ Xe,
        const float* __restrict__ Be, float* __restrict__ dots) {
    __shared__ float At[64 * 68];        // [b_s][k]
    __shared__ float Bt[64 * 68];        // [k][b_b]  (k-major!)
    const int s0 = blockIdx.y * 64, b0 = blockIdx.x * 64;
    const int tid = threadIdx.x;
    const int ts = tid >> 4, tb = tid & 15;       // tb fast -> contiguous stores
    float acc[4][4] = {};
    for (int kt = 0; kt < 2; ++kt) {
        __syncthreads();
        #pragma unroll
        for (int it = 0; it < 4; ++it) {
            int idx = tid * 4 + it * 1024;
            int r = idx >> 6, k = idx & 63;
            *(float4*)(&At[r * 68 + k]) = *(const float4*)(Xe + (size_t)(s0 + r) * NH + kt * 64 + k);
            float4 bvv = *(const float4*)(Be + (size_t)(b0 + r) * NH + kt * 64 + k);
            Bt[(k + 0) * 68 + r] = bvv.x;
            Bt[(k + 1) * 68 + r] = bvv.y;
            Bt[(k + 2) * 68 + r] = bvv.z;
            Bt[(k + 3) * 68 + r] = bvv.w;
        }
        __syncthreads();
        #pragma unroll 4
        for (int k = 0; k < 64; ++k) {
            float4 bq = *(const float4*)(&Bt[k * 68 + tb * 4]);   // one ds_read_b128
            float a[4];
            #pragma unroll
            for (int i = 0; i < 4; ++i) a[i] = At[(ts + 16 * i) * 68 + k];
            #pragma unroll
            for (int i = 0; i < 4; ++i) {
                acc[i][0] = fmaf(a[i], bq.x, acc[i][0]);
                acc[i][1] = fmaf(a[i], bq.y, acc[i][1]);
                acc[i][2] = fmaf(a[i], bq.z, acc[i][2]);
                acc[i][3] = fmaf(a[i], bq.w, acc[i][3]);
            }
        }
    }
    #pragma unroll
    for (int i = 0; i < 4; ++i) {
        float4 v = make_float4(acc[i][0], acc[i][1], acc[i][2], acc[i][3]);
        *(float4*)(&dots[(size_t)(s0 + ts + 16 * i) * NB + b0 + tb * 4]) = v;
    }
}

// ---------- softmax + MFMA einsum (xs|y|den via extended B), one block per s ----------
__global__ __launch_bounds__(256) void fusedA_k(float* __restrict__ dots,
        const unsigned long long* __restrict__ pmask,
        const unsigned short* __restrict__ bgXT2,
        float* __restrict__ rden_g, float* __restrict__ out) {
    __shared__ __align__(16) unsigned int mrow[NB];      // 8KB: mask bits, word b bit t
    __shared__ __align__(16) unsigned short e_bf[NB];    // 4KB: bf16(e)
    __shared__ float part[3 * NT * NFX];                 // 30KB: cross-wave partials
    __shared__ float wmax[4];
    __shared__ float rden_l[NT];
    __shared__ float ytmp[NT];

    const int s = blockIdx.x;
    const int tid = threadIdx.x;
    const int lane = tid & 63, w = tid >> 6;
    const int lo = lane & 15, hi = lane >> 4;

    // ---- phase 1: row max (shfl) + exp; e -> global f32 (for alphas_k) + LDS bf16 ----
    float* drow = dots + (size_t)s * NB;
    float4 d0 = *(const float4*)(drow + tid * 8);
    float4 d1 = *(const float4*)(drow + tid * 8 + 4);
    const uint4* pmrow = (const uint4*)((const unsigned int*)pmask + (size_t)s * NB);
    *(uint4*)(&mrow[tid * 4]) = pmrow[tid];
    *(uint4*)(&mrow[(tid + 256) * 4]) = pmrow[tid + 256];
    float pmax = fmaxf(fmaxf(fmaxf(d0.x, d0.y), fmaxf(d0.z, d0.w)),
                       fmaxf(fmaxf(d1.x, d1.y), fmaxf(d1.z, d1.w)));
    #pragma unroll
    for (int off = 32; off >= 1; off >>= 1)
        pmax = fmaxf(pmax, __shfl_xor(pmax, off, 64));
    if (lane == 0) wmax[w] = pmax;
    __syncthreads();
    const float Ms = fmaxf(fmaxf(wmax[0], wmax[1]), fmaxf(wmax[2], wmax[3]));
    float ev[8] = {d0.x, d0.y, d0.z, d0.w, d1.x, d1.y, d1.z, d1.w};
    union { unsigned short u[8]; uint4 q; } epk;
    #pragma unroll
    for (int q = 0; q < 8; ++q) { ev[q] = __expf(ev[q] - Ms); epk.u[q] = f2bfu(ev[q]); }
    *(float4*)(drow + tid * 8)     = make_float4(ev[0], ev[1], ev[2], ev[3]);
    *(float4*)(drow + tid * 8 + 4) = make_float4(ev[4], ev[5], ev[6], ev[7]);
    *(uint4*)(&e_bf[tid * 8]) = epk.q;
    __syncthreads();

    // ---- phase 2: MFMA over K; B-frags from fragment-ordered fb (1KB/instr/wave) ----
    f32x4 acc[2][5] = {};
    const uint4* fb = (const uint4*)bgXT2;
    #pragma unroll 2
    for (int ks = 0; ks < 16; ++ks) {
        const int bb = w * 512 + ks * 32 + hi * 8;
        uint4 ew4 = *(const uint4*)(&e_bf[bb]);
        uint4 m0 = *(const uint4*)(&mrow[bb]);
        uint4 m1 = *(const uint4*)(&mrow[bb + 4]);
        unsigned int ew[4] = {ew4.x, ew4.y, ew4.z, ew4.w};
        unsigned int mv[8] = {m0.x, m0.y, m0.z, m0.w, m1.x, m1.y, m1.z, m1.w};
        unsigned int A0[4], A1[4];
        #pragma unroll
        for (int p = 0; p < 4; ++p) {
            unsigned int mlo = mv[2 * p]     >> lo;
            unsigned int mhi = mv[2 * p + 1] >> lo;
            unsigned int k0 = ((mlo & 1u)       ? 0x0000FFFFu : 0u) |
                              ((mhi & 1u)       ? 0xFFFF0000u : 0u);
            unsigned int k1 = ((mlo & 0x10000u) ? 0x0000FFFFu : 0u) |
                              ((mhi & 0x10000u) ? 0xFFFF0000u : 0u);
            A0[p] = ew[p] & k0;
            A1[p] = ew[p] & k1;
        }
        bf16x8 a0 = __builtin_bit_cast(bf16x8, make_uint4(A0[0], A0[1], A0[2], A0[3]));
        bf16x8 a1 = __builtin_bit_cast(bf16x8, make_uint4(A1[0], A1[1], A1[2], A1[3]));
        const uint4* fr = fb + ((size_t)(w * 16 + ks) * 5) * 64 + lane;
        #pragma unroll
        for (int n = 0; n < 5; ++n) {
            uint4 bv = fr[n * 64];
            bf16x8 bfr = __builtin_bit_cast(bf16x8, bv);
            acc[0][n] = __builtin_amdgcn_mfma_f32_16x16x32_bf16(a0, bfr, acc[0][n], 0, 0, 0);
            acc[1][n] = __builtin_amdgcn_mfma_f32_16x16x32_bf16(a1, bfr, acc[1][n], 0, 0, 0);
        }
    }

    // ---- phase 3: cross-wave reduce; den/y from cols 65/64; write leaf_xs/leaf_y ----
    if (w > 0) {
        #pragma unroll
        for (int m = 0; m < 2; ++m)
            #pragma unroll
            for (int n = 0; n < 5; ++n)
                #pragma unroll
                for (int r = 0; r < 4; ++r) {
                    int t = m * 16 + hi * 4 + r, f = n * 16 + lo;
                    part[(w - 1) * (NT * NFX) + t * NFX + f] = acc[m][n][r];
                }
    }
    __syncthreads();
    if (w == 0) {
        #pragma unroll
        for (int m = 0; m < 2; ++m)
            #pragma unroll
            for (int r = 0; r < 4; ++r) {
                int t = m * 16 + hi * 4 + r;
                int o = t * NFX + 64 + lo;
                float tot = acc[m][4][r] + part[o] + part[NT * NFX + o] + part[2 * NT * NFX + o];
                if (lo == 0) ytmp[t] = tot;
                if (lo == 1) rden_l[t] = (tot > 0.f) ? 1.f / tot : 0.f;
            }
    }
    __syncthreads();
    if (w == 0) {
        float* xout = out + (size_t)s * NT * NF;
        #pragma unroll
        for (int m = 0; m < 2; ++m)
            #pragma unroll
            for (int n = 0; n < 4; ++n)
                #pragma unroll
                for (int r = 0; r < 4; ++r) {
                    int t = m * 16 + hi * 4 + r, f = n * 16 + lo;
                    int o = t * NFX + f;
                    float tot = acc[m][n][r] + part[o] + part[NT * NFX + o] + part[2 * NT * NFX + o];
                    xout[t * NF + f] = tot * rden_l[t];
                }
    }
    if (tid < 32) {
        out[OY + (size_t)s * NT + tid] = ytmp[tid] * rden_l[tid];
        rden_g[(size_t)s * NT + tid] = rden_l[tid];
    }
}

// ---------- alphas streaming write: 4096 blocks (measured 6.3 TB/s = at floor) ----------
__global__ __launch_bounds__(256) void alphas_k(const float* __restrict__ e,
        const unsigned int* __restrict__ pmask32, const float* __restrict__ rden_g,
        float* __restrict__ out) {
    const int tid = threadIdx.x;
    const int blk = blockIdx.x;               // 4096 blocks: (s, eighth)
    const int s = blk >> 3;
    const int tq = tid & 7;
    const f32x4 rd4 = *(const f32x4*)(rden_g + (size_t)s * NT + tq * 4);
    const float* erow = e + (size_t)s * NB;
    const unsigned int* mr = pmask32 + (size_t)s * NB;
    float* aout = out + OA + (size_t)s * NB * NT;
    const int b0 = (blk & 7) * 256 + (tid >> 3);

    float ev[8];
    unsigned int mv[8];
    #pragma unroll
    for (int j = 0; j < 8; ++j) {
        ev[j] = erow[b0 + j * 32];
        mv[j] = mr[b0 + j * 32] >> (tq * 4);
    }
    #pragma unroll
    for (int j = 0; j < 8; ++j) {
        const int b = b0 + j * 32;
        f32x4 v;
        v.x = (mv[j] & 1u) ? ev[j] * rd4.x : 0.f;
        v.y = (mv[j] & 2u) ? ev[j] * rd4.y : 0.f;
        v.z = (mv[j] & 4u) ? ev[j] * rd4.z : 0.f;
        v.w = (mv[j] & 8u) ? ev[j] * rd4.w : 0.f;
        *(f32x4*)(aout + (size_t)b * NT + tq * 4) = v;
    }
}

extern "C" void kernel_launch(void* const* d_in, const int* in_sizes, int n_in,
                              void* d_out, int out_size, void* d_ws, size_t ws_size,
                              hipStream_t stream) {
    (void)in_sizes; (void)n_in; (void)out_size; (void)ws_size;
    const float* X   = (const float*)d_in[0];
    const float* bgX = (const float*)d_in[1];
    const float* bgy = (const float*)d_in[2];
    const void*  nh  = d_in[3];
    const float* W1  = (const float*)d_in[4];
    const float* b1v = (const float*)d_in[5];
    const float* W2  = (const float*)d_in[6];
    const float* b2v = (const float*)d_in[7];
    float* out = (float*)d_out;
    char* ws = (char*)d_ws;

    // ws layout (bytes): [pad 4096][enc: 2560*128 f32 — rden_g overlays its head,
    //  safe: enc dead after dots_k][dots/e: 512*2048 f32][pmask: 4MB u64][fb: 320KB]
    float* enc = (float*)(ws + 4096);
    float* rden_g = (float*)(ws + 4096);   // overlays enc (enc consumed before fusedA writes)
    float* Xe = enc;
    float* Be = enc + (size_t)NS * NH;
    float* dots = (float*)(ws + 4096 + (size_t)(NS + NB) * NH * 4);
    unsigned long long* pmask = (unsigned long long*)((char*)dots + (size_t)NS * NB * 4);
    unsigned short* bgXT2 = (unsigned short*)((char*)pmask + (size_t)NS * NB * NT / 64 * 8);

    prep_k<<<PACK_B + ENC_B + TR_B, 256, 0, stream>>>(nh, pmask, X, bgX, bgy,
                                                      W1, b1v, W2, b2v, enc, bgXT2);
    dots_k<<<dim3(NB / 64, NS / 64), 256, 0, stream>>>(Xe, Be, dots);
    fusedA_k<<<NS, 256, 0, stream>>>(dots, pmask, bgXT2, rden_g, out);
    alphas_k<<<NS * 8, 256, 0, stream>>>(dots, (const unsigned int*)pmask, rden_g, out);
}